// Round 4
// baseline (155.794 us; speedup 1.0000x reference)
//
#include <hip/hip_runtime.h>
#include <hip/hip_fp16.h>

// MinGRU fused pipeline, round 4.
// 1) gemm_fused: reads fp32 x/Wz/Wh directly (no convert pass). Global fp32
//    loads issued before the barrier (overlap prior MFMA phase), converted
//    in-register to bf16, ds_write into pad-72 LDS (conflict-free), bf16 MFMA
//    16x16x32, fused sigmoid epilogue -> interleaved (a,bb) fp16 half2 +
//    per-sub-chunk (L=32) affine summaries via LDS overlay.
// 2) combine: sequential affine compose over 128 chunk summaries -> hstart.
// 3) apply:   per-chunk recurrence from hstart, writes fp32 output.

namespace {
constexpr int kB  = 8;
constexpr int kT  = 4096;
constexpr int kD  = 256;
constexpr int kH  = 256;
constexpr int kBT = kB * kT;
constexpr int kL  = 32;           // scan chunk length
constexpr int kNC = kT / kL;      // 128 chunks per sequence

constexpr int TM  = 128;          // GEMM row (time) tile
constexpr int TH  = 64;           // GEMM h tile (dual-W => 128 effective N)
constexpr int BK  = 64;           // GEMM k tile
constexpr int LDP = 72;           // staging LDS row stride (ushort) - depads banks
constexpr int EPS = 66;           // epilogue LDS row stride (half)
} // namespace

typedef short s16x8 __attribute__((ext_vector_type(8)));
typedef short s16x4 __attribute__((ext_vector_type(4)));
typedef float f32x4 __attribute__((ext_vector_type(4)));

__device__ __forceinline__ short f2bf(float f) {
    union { float f; unsigned int u; } v; v.f = f;
    unsigned int r = v.u + 0x7fffu + ((v.u >> 16) & 1u);   // RNE
    return (short)(r >> 16);
}
__device__ __forceinline__ s16x4 cvt4(float4 v) {
    s16x4 p;
    p[0] = f2bf(v.x); p[1] = f2bf(v.y); p[2] = f2bf(v.z); p[3] = f2bf(v.w);
    return p;
}

// ---------------------------------------------------------------------------
// Kernel 1: dual GEMM (fp32 in, bf16 MFMA) + sigmoid + (a,bb) half2 store +
// sub-chunk affine summaries. Grid: (kH/TH = 4, kBT/TM = 256), 4 waves/block.
// ---------------------------------------------------------------------------
__global__ __launch_bounds__(256, 3)
void gemm_fused(const float* __restrict__ x,
                const float* __restrict__ Wz,
                const float* __restrict__ bz,
                const float* __restrict__ Wh,
                const float* __restrict__ bh,
                __half2* __restrict__ ab_ws,     // [kBT][kH] (a,bb)
                float2* __restrict__ ABsum)      // [kB*kNC][kH] (A,Bv)
{
    // 36.9 KB: staging Xs[128][72] | Wzs[64][72] | Whs[64][72] (ushort),
    // overlaid after the K loop by a_lds/b_lds [128][66] (half).
    __shared__ __align__(16) unsigned char smem[36864];
    unsigned short* Xs  = (unsigned short*)smem;
    unsigned short* Wzs = Xs  + 128 * LDP;
    unsigned short* Whs = Wzs + 64 * LDP;
    __half* a_lds = (__half*)smem;               // [128][EPS]
    __half* b_lds = a_lds + 128 * EPS;

    const int tid  = threadIdx.x;
    const int lane = tid & 63;
    const int wv   = tid >> 6;
    const int ln15 = lane & 15;
    const int quad = lane >> 4;
    const int wr0  = (wv & 1) * 64;     // wave row offset
    const int wc0  = (wv >> 1) * 32;    // wave h-col offset
    const int row0 = blockIdx.y * TM;
    const int col0 = blockIdx.x * TH;

    const int srow = tid >> 4;          // 0..15 staging row-in-pass
    const int sc4  = (tid & 15) * 4;    // staging k offset (floats)

    f32x4 accZ[4][2] = {};
    f32x4 accU[4][2] = {};

    for (int k0 = 0; k0 < kD; k0 += BK) {
        // ---- issue global fp32 loads (overlap previous tile's MFMA phase)
        float4 xv[8], wzv[4], whv[4];
        #pragma unroll
        for (int p = 0; p < 8; ++p)
            xv[p] = *(const float4*)(x + (size_t)(row0 + p * 16 + srow) * kD + k0 + sc4);
        #pragma unroll
        for (int p = 0; p < 4; ++p) {
            wzv[p] = *(const float4*)(Wz + (size_t)(col0 + p * 16 + srow) * kD + k0 + sc4);
            whv[p] = *(const float4*)(Wh + (size_t)(col0 + p * 16 + srow) * kD + k0 + sc4);
        }
        __syncthreads();   // previous MFMA phase done reading LDS

        // ---- convert + stage
        #pragma unroll
        for (int p = 0; p < 8; ++p)
            *(s16x4*)&Xs[(p * 16 + srow) * LDP + sc4] = cvt4(xv[p]);
        #pragma unroll
        for (int p = 0; p < 4; ++p) {
            *(s16x4*)&Wzs[(p * 16 + srow) * LDP + sc4] = cvt4(wzv[p]);
            *(s16x4*)&Whs[(p * 16 + srow) * LDP + sc4] = cvt4(whv[p]);
        }
        __syncthreads();

        // ---- MFMA over this k tile (two K=32 chunks)
        #pragma unroll
        for (int kk = 0; kk < BK; kk += 32) {
            s16x8 af[4], bzf[2], buf[2];
            #pragma unroll
            for (int mt = 0; mt < 4; ++mt)
                af[mt] = *(const s16x8*)&Xs[(wr0 + mt * 16 + ln15) * LDP + kk + quad * 8];
            #pragma unroll
            for (int nt = 0; nt < 2; ++nt) {
                bzf[nt] = *(const s16x8*)&Wzs[(wc0 + nt * 16 + ln15) * LDP + kk + quad * 8];
                buf[nt] = *(const s16x8*)&Whs[(wc0 + nt * 16 + ln15) * LDP + kk + quad * 8];
            }
            #pragma unroll
            for (int mt = 0; mt < 4; ++mt) {
                #pragma unroll
                for (int nt = 0; nt < 2; ++nt) {
                    accZ[mt][nt] = __builtin_amdgcn_mfma_f32_16x16x32_bf16(
                        af[mt], bzf[nt], accZ[mt][nt], 0, 0, 0);
                    accU[mt][nt] = __builtin_amdgcn_mfma_f32_16x16x32_bf16(
                        af[mt], buf[nt], accU[mt][nt], 0, 0, 0);
                }
            }
        }
    }
    __syncthreads();   // done with staging LDS; safe to overlay

    // ---- epilogue: sigmoid; a/bb to LDS (C/D: col=ln15, row=quad*4+r  [m89])
    #pragma unroll
    for (int nt = 0; nt < 2; ++nt) {
        const int col = col0 + wc0 + nt * 16 + ln15;
        const int lc  = wc0 + nt * 16 + ln15;
        const float bzv = bz[col];
        const float bhv = bh[col];
        #pragma unroll
        for (int mt = 0; mt < 4; ++mt) {
            const int rb = wr0 + mt * 16 + quad * 4;
            #pragma unroll
            for (int r = 0; r < 4; ++r) {
                const float z = accZ[mt][nt][r] + bzv;
                const float g = 1.0f / (1.0f + __expf(-z));
                const float u = accU[mt][nt][r] + bhv;
                a_lds[(rb + r) * EPS + lc] = __float2half_rn(1.0f - g);
                b_lds[(rb + r) * EPS + lc] = __float2half_rn(g * u);
            }
        }
    }
    __syncthreads();

    // ---- coalesced interleaved (a,bb) global write: 8 B/thread/iter
    #pragma unroll
    for (int it = 0; it < 16; ++it) {
        const int q  = tid + it * 256;        // 0..4095
        const int t  = q >> 5;                // 0..127
        const int hp = (q & 31) * 2;          // 0,2,..,62
        const __half a0 = a_lds[t * EPS + hp],     a1 = a_lds[t * EPS + hp + 1];
        const __half b0 = b_lds[t * EPS + hp],     b1 = b_lds[t * EPS + hp + 1];
        __half2* dst = ab_ws + (size_t)(row0 + t) * kH + col0 + hp;
        dst[0] = __halves2half2(a0, b0);
        dst[1] = __halves2half2(a1, b1);
    }

    // ---- sub-chunk affine summaries: 4 sub-chunks (L=32) x 64 h
    {
        const int s = tid >> 6;
        const int h = tid & 63;
        float A = 1.0f, Bv = 0.0f;
        #pragma unroll 8
        for (int t = s * 32; t < s * 32 + 32; ++t) {
            const float a  = __half2float(a_lds[t * EPS + h]);
            const float bb = __half2float(b_lds[t * EPS + h]);
            Bv = fmaf(a, Bv, bb);
            A *= a;
        }
        const int b = row0 / kT;
        const int c = (row0 % kT) / kL + s;
        float2 o; o.x = A; o.y = Bv;
        ABsum[(size_t)(b * kNC + c) * kH + col0 + h] = o;
    }
}

// ---------------------------------------------------------------------------
// Kernel 2: sequential combine over chunk summaries -> h at each chunk start.
// ---------------------------------------------------------------------------
__global__ __launch_bounds__(256)
void combine(const float* __restrict__ h0,
             const float2* __restrict__ ABsum,
             float* __restrict__ hstart)
{
    const int b = blockIdx.x;
    const int h = threadIdx.x;
    float hv = h0[(size_t)b * kH + h];
    #pragma unroll 8
    for (int c = 0; c < kNC; ++c) {
        const size_t idx = (size_t)(b * kNC + c) * kH + h;
        hstart[idx] = hv;
        const float2 ab = ABsum[idx];
        hv = fmaf(ab.x, hv, ab.y);
    }
}

// ---------------------------------------------------------------------------
// Kernel 3: apply recurrence within each chunk from its known h_start.
// ---------------------------------------------------------------------------
__global__ __launch_bounds__(256)
void apply_scan(const __half2* __restrict__ ab_ws,
                const float* __restrict__ hstart,
                float* __restrict__ out)
{
    const int c = blockIdx.x & (kNC - 1);
    const int b = blockIdx.x >> 7;            // kNC = 128
    const int h = threadIdx.x;

    float hv = hstart[(size_t)(b * kNC + c) * kH + h];
    const size_t base = ((size_t)b * kT + (size_t)c * kL) * kH + h;
    #pragma unroll 8
    for (int t = 0; t < kL; ++t) {
        const __half2 ab = ab_ws[base + (size_t)t * kH];
        hv = fmaf(__low2float(ab), hv, __high2float(ab));
        out[base + (size_t)t * kH] = hv;
    }
}

extern "C" void kernel_launch(void* const* d_in, const int* in_sizes, int n_in,
                              void* d_out, int out_size, void* d_ws, size_t ws_size,
                              hipStream_t stream)
{
    const float* x  = (const float*)d_in[0];
    const float* h0 = (const float*)d_in[1];
    const float* Wz = (const float*)d_in[2];
    const float* bz = (const float*)d_in[3];
    const float* Wh = (const float*)d_in[4];
    const float* bh = (const float*)d_in[5];
    float* out = (float*)d_out;

    // Workspace: ab 33.55M | ABsum 2.10M | hstart 1.05M  => ~36.7 MB.
    unsigned char* ws = (unsigned char*)d_ws;
    __half2* ab_ws = (__half2*)ws;        ws += (size_t)kBT * kH * 4;
    float2* ABsum  = (float2*)ws;         ws += (size_t)kB * kNC * kH * 8;
    float* hstart  = (float*)ws;

    gemm_fused<<<dim3(kH / TH, kBT / TM), 256, 0, stream>>>(
        x, Wz, bz, Wh, bh, ab_ws, ABsum);
    combine<<<kB, kH, 0, stream>>>(h0, ABsum, hstart);
    apply_scan<<<kB * kNC, kH, 0, stream>>>(ab_ws, hstart, out);
}

// Round 5
// 118.051 us; speedup vs baseline: 1.3197x; 1.3197x over previous
//
#include <hip/hip_runtime.h>
#include <hip/hip_fp16.h>

// MinGRU single-pass fused pipeline, round 5.
// prologue: x,Wz,Wh fp32->bf16 + zero the aggregate mailbox (512 KB).
// gemm_scan_fused: round-3 async-staged bf16 MFMA GEMM (128x64 tile, BK=64,
//   dual-W, global_load_lds width=16) -> sigmoid epilogue into LDS (fp16)
//   -> per-block affine aggregate -> publish as 8B device-scope atomic
//   (payload-in-atomic; LSB|=1 so 0 == not-ready) -> decoupled lookback over
//   <=31 predecessors (independent per h, no serial chain) -> apply recurrence
//   from LDS -> write out directly. No ab round-trip, no combine/apply kernels.
// Deadlock safety: 1024 blocks, 36.4KB LDS + launch_bounds(256,4) => 4
// blocks/CU, all 1024 co-resident; grid (chain=32, t=32) with t slower-varying
// so predecessors dispatch first; a block only waits on lower blockIdx.y.

namespace {
constexpr int kB  = 8;
constexpr int kT  = 4096;
constexpr int kD  = 256;
constexpr int kH  = 256;
constexpr int kBT = kB * kT;

constexpr int TM  = 128;          // time rows per block
constexpr int TH  = 64;           // h cols per block (dual-W => 128 eff. N)
constexpr int BK  = 64;           // GEMM k tile
constexpr int kNT = kT / TM;      // 32 time-tiles per sequence (chain length)
constexpr int kNChain = kB * (kH / TH);   // 32 chains
constexpr int EPS = 66;           // epilogue LDS row stride (half)
} // namespace

typedef short s16x8 __attribute__((ext_vector_type(8)));
typedef short s16x4 __attribute__((ext_vector_type(4)));
typedef float f32x4 __attribute__((ext_vector_type(4)));

__device__ __forceinline__ short f2bf(float f) {
    union { float f; unsigned int u; } v; v.f = f;
    unsigned int r = v.u + 0x7fffu + ((v.u >> 16) & 1u);   // RNE
    return (short)(r >> 16);
}

__device__ __forceinline__ void load_lds16(const void* g, void* l) {
    __builtin_amdgcn_global_load_lds(
        (const __attribute__((address_space(1))) void*)g,
        (__attribute__((address_space(3))) void*)l, 16, 0, 0);
}

// ---------------------------------------------------------------------------
// Kernel 1: fp32 -> bf16 for x, Wz, Wh; zero the 512 KB aggregate mailbox.
// ---------------------------------------------------------------------------
__global__ __launch_bounds__(256)
void prologue(const float* __restrict__ x,
              const float* __restrict__ Wz,
              const float* __restrict__ Wh,
              unsigned short* __restrict__ xb,
              unsigned short* __restrict__ wzb,
              unsigned short* __restrict__ whb,
              float4* __restrict__ aggz)
{
    constexpr int X4 = kBT * kD / 4;          // 2,097,152
    constexpr int W4 = kH  * kD / 4;          // 16,384 each
    constexpr int Z4 = kNChain * kNT * TH * 8 / 16;   // 32,768 float4 zeros
    const int i = blockIdx.x * 256 + threadIdx.x;     // < X4 + 2*W4 + Z4

    if (i >= X4 + 2 * W4) {                   // zero mailbox
        float4 z; z.x = 0.f; z.y = 0.f; z.z = 0.f; z.w = 0.f;
        aggz[i - (X4 + 2 * W4)] = z;
        return;
    }
    const float* src; unsigned short* dst; int j;
    if (i < X4)           { src = x;  dst = xb;  j = i; }
    else if (i < X4 + W4) { src = Wz; dst = wzb; j = i - X4; }
    else                  { src = Wh; dst = whb; j = i - X4 - W4; }
    const float4 v = ((const float4*)src)[j];
    s16x4 p;
    p[0] = f2bf(v.x); p[1] = f2bf(v.y); p[2] = f2bf(v.z); p[3] = f2bf(v.w);
    ((s16x4*)dst)[j] = p;
}

// ---------------------------------------------------------------------------
// Kernel 2: GEMM + sigmoid + block aggregate + lookback + apply + out.
// Grid: dim3(kNChain=32, kNT=32). 4 waves/block.
// ---------------------------------------------------------------------------
__global__ __launch_bounds__(256, 4)
void gemm_scan_fused(const unsigned short* __restrict__ xb,
                     const unsigned short* __restrict__ wzb,
                     const unsigned short* __restrict__ whb,
                     const float* __restrict__ bz,
                     const float* __restrict__ bh,
                     const float* __restrict__ h0,
                     unsigned long long* __restrict__ agg,  // [32 chains][32 t][64 h]
                     float* __restrict__ out)
{
    // LDS: staging Xs[128][64] | Wzs[64][64] | Whs[64][64] (ushort, 32KB),
    // overlaid after K loop by a_lds/b_lds [128][66] half (33.8KB);
    // + sub_lds[4][64] float2 @33792 ; + hs_lds[64] float @35840.
    __shared__ __align__(16) unsigned char smem[36096];
    unsigned short* Xs  = (unsigned short*)smem;
    unsigned short* Wzs = Xs  + 128 * 64;
    unsigned short* Whs = Wzs + 64 * 64;
    __half* a_lds   = (__half*)smem;                 // [128][EPS]
    __half* b_lds   = a_lds + 128 * EPS;
    float2* sub_lds = (float2*)(smem + 33792);       // [4][64]
    float*  hs_lds  = (float*)(smem + 35840);        // [64]

    const int tid  = threadIdx.x;
    const int lane = tid & 63;
    const int wv   = tid >> 6;
    const int ln15 = lane & 15;
    const int quad = lane >> 4;
    const int wr0  = (wv & 1) * 64;
    const int wc0  = (wv >> 1) * 32;

    const int chain = blockIdx.x;            // 0..31
    const int t     = blockIdx.y;            // 0..31 (time-tile in chain)
    const int b     = chain >> 2;
    const int col0  = (chain & 3) * TH;
    const int row0  = b * kT + t * TM;       // global BT row of tile top

    const int srow = lane >> 3;              // 0..7
    const int sk   = (lane & 7) * 8;         // k element offset

    f32x4 accZ[4][2] = {};
    f32x4 accU[4][2] = {};

    for (int k0 = 0; k0 < kD; k0 += BK) {
        #pragma unroll
        for (int s = 0; s < 4; ++s) {
            const int seg = wv * 4 + s;
            const int m = seg * 8 + srow;
            load_lds16(xb + (size_t)(row0 + m) * kD + k0 + sk, Xs + seg * 512);
        }
        #pragma unroll
        for (int s = 0; s < 2; ++s) {
            const int seg = wv * 2 + s;
            const int m = seg * 8 + srow;
            load_lds16(wzb + (size_t)(col0 + m) * kD + k0 + sk, Wzs + seg * 512);
            load_lds16(whb + (size_t)(col0 + m) * kD + k0 + sk, Whs + seg * 512);
        }
        __syncthreads();   // drains the DMA (vmcnt0 before barrier)

        #pragma unroll
        for (int kk = 0; kk < BK; kk += 32) {
            s16x8 af[4], bzf[2], buf[2];
            #pragma unroll
            for (int mt = 0; mt < 4; ++mt)
                af[mt] = *(const s16x8*)&Xs[(wr0 + mt * 16 + ln15) * 64 + kk + quad * 8];
            #pragma unroll
            for (int nt = 0; nt < 2; ++nt) {
                bzf[nt] = *(const s16x8*)&Wzs[(wc0 + nt * 16 + ln15) * 64 + kk + quad * 8];
                buf[nt] = *(const s16x8*)&Whs[(wc0 + nt * 16 + ln15) * 64 + kk + quad * 8];
            }
            #pragma unroll
            for (int mt = 0; mt < 4; ++mt) {
                #pragma unroll
                for (int nt = 0; nt < 2; ++nt) {
                    accZ[mt][nt] = __builtin_amdgcn_mfma_f32_16x16x32_bf16(
                        af[mt], bzf[nt], accZ[mt][nt], 0, 0, 0);
                    accU[mt][nt] = __builtin_amdgcn_mfma_f32_16x16x32_bf16(
                        af[mt], buf[nt], accU[mt][nt], 0, 0, 0);
                }
            }
        }
        __syncthreads();
    }

    // ---- epilogue: sigmoid; a/bb -> LDS fp16 (C/D: col=ln15, row=quad*4+r)
    #pragma unroll
    for (int nt = 0; nt < 2; ++nt) {
        const int col = col0 + wc0 + nt * 16 + ln15;
        const int lc  = wc0 + nt * 16 + ln15;
        const float bzv = bz[col];
        const float bhv = bh[col];
        #pragma unroll
        for (int mt = 0; mt < 4; ++mt) {
            const int rb = wr0 + mt * 16 + quad * 4;
            #pragma unroll
            for (int r = 0; r < 4; ++r) {
                const float z = accZ[mt][nt][r] + bzv;
                const float g = 1.0f / (1.0f + __expf(-z));
                const float u = accU[mt][nt][r] + bhv;
                a_lds[(rb + r) * EPS + lc] = __float2half_rn(1.0f - g);
                b_lds[(rb + r) * EPS + lc] = __float2half_rn(g * u);
            }
        }
    }
    __syncthreads();

    // ---- sub-chunk (32-row) affine summaries: thread (s,h)
    const int s = tid >> 6;
    const int h = tid & 63;
    {
        float A = 1.0f, Bv = 0.0f;
        #pragma unroll 8
        for (int r = s * 32; r < s * 32 + 32; ++r) {
            const float a  = __half2float(a_lds[r * EPS + h]);
            const float bb = __half2float(b_lds[r * EPS + h]);
            Bv = fmaf(a, Bv, bb);
            A *= a;
        }
        float2 o; o.x = A; o.y = Bv;
        sub_lds[s * 64 + h] = o;
    }
    __syncthreads();

    // ---- publish block aggregate + lookback (wave 0, one lane per h)
    if (tid < 64) {
        float A = 1.0f, Bv = 0.0f;
        #pragma unroll
        for (int s2 = 0; s2 < 4; ++s2) {
            const float2 g = sub_lds[s2 * 64 + tid];
            Bv = fmaf(g.x, Bv, g.y);
            A *= g.x;
        }
        union { float2 f; unsigned long long u; } pk;
        pk.f.x = A; pk.f.y = Bv;
        pk.u |= 1ull;                         // never 0 => unambiguous ready flag
        __hip_atomic_store(&agg[(size_t)(chain * kNT + t) * 64 + tid], pk.u,
                           __ATOMIC_RELAXED, __HIP_MEMORY_SCOPE_AGENT);

        // lookback: fold predecessors 0..t-1 (independent per h; all aggregates
        // appear ~simultaneously, so no serial chain).
        float hs = h0[(size_t)b * kH + col0 + tid];
        for (int j = 0; j < t; ++j) {
            unsigned long long u;
            do {
                u = __hip_atomic_load(&agg[(size_t)(chain * kNT + j) * 64 + tid],
                                      __ATOMIC_RELAXED, __HIP_MEMORY_SCOPE_AGENT);
            } while (u == 0ull);
            union { unsigned long long u; float2 f; } qk; qk.u = u;
            hs = fmaf(qk.f.x, hs, qk.f.y);
        }
        hs_lds[tid] = hs;
    }
    __syncthreads();

    // ---- apply recurrence: thread (s,h) does its 32 rows, writes out
    {
        float hv = hs_lds[h];
        #pragma unroll
        for (int s2 = 0; s2 < s; ++s2) {
            const float2 g = sub_lds[s2 * 64 + h];
            hv = fmaf(g.x, hv, g.y);
        }
        #pragma unroll 8
        for (int r = 0; r < 32; ++r) {
            const int lr = s * 32 + r;
            const float a  = __half2float(a_lds[lr * EPS + h]);
            const float bb = __half2float(b_lds[lr * EPS + h]);
            hv = fmaf(a, hv, bb);
            out[(size_t)(row0 + lr) * kH + col0 + h] = hv;
        }
    }
}

extern "C" void kernel_launch(void* const* d_in, const int* in_sizes, int n_in,
                              void* d_out, int out_size, void* d_ws, size_t ws_size,
                              hipStream_t stream)
{
    const float* x  = (const float*)d_in[0];
    const float* h0 = (const float*)d_in[1];
    const float* Wz = (const float*)d_in[2];
    const float* bz = (const float*)d_in[3];
    const float* Wh = (const float*)d_in[4];
    const float* bh = (const float*)d_in[5];
    float* out = (float*)d_out;

    // Workspace: xb 16.78M | wzb/whb 131K each | agg 512K  => ~17.6 MB.
    unsigned char* ws = (unsigned char*)d_ws;
    unsigned short* xb  = (unsigned short*)ws;   ws += (size_t)kBT * kD * 2;
    unsigned short* wzb = (unsigned short*)ws;   ws += (size_t)kH * kD * 2;
    unsigned short* whb = (unsigned short*)ws;   ws += (size_t)kH * kD * 2;
    unsigned long long* agg = (unsigned long long*)ws;

    constexpr int PRO_ITEMS = kBT * kD / 4 + 2 * (kH * kD / 4)
                            + kNChain * kNT * TH * 8 / 16;   // 2,162,688
    prologue<<<PRO_ITEMS / 256, 256, 0, stream>>>(
        x, Wz, Wh, xb, wzb, whb, (float4*)agg);
    gemm_scan_fused<<<dim3(kNChain, kNT), 256, 0, stream>>>(
        xb, wzb, whb, bz, bh, h0, agg, out);
}